// Round 7
// baseline (752.971 us; speedup 1.0000x reference)
//
#include <hip/hip_runtime.h>
#include <stdint.h>

// QuantizedLinear: C[8192,4096] = X[8192,4096] @ W[4096,4096]^T * (1/127)
// Strategy: X split into hi+lo bf16 (near-fp32 precision: err <= 2^-16 rel),
// W exact in bf16 (values 0..126). m97-style 128x128xBK64 MFMA GEMM,
// global_load_lds width-16 staging, single LDS buffer, T1 XCD swizzle.
// R2: hi split uses round-to-nearest -> residual <= 2^-8 |x|, exact subtract.
// R3: full address-algebra audit (staging / fragments / epilogue).
// R4: prep kernels grid-stride at 2048 blocks (G11).
// R5: blind 8-phase port rejected on EV (race risk wastes first green bench);
//     K'=8192 reformulation rejected at THIS structure (loses B-frag reuse).
// R6: end-to-end error bound re-derived (rms ~2.4e-4, worst ~1.2e-3 on
//     outputs of std ~37) — numerics safe. Kernel held; ladder unchanged:
//     green bench -> K'=8192 2-operand -> 8-phase 256^2 -> T2 -> T5.

#define M_DIM 8192
#define N_DIM 4096
#define K_DIM 4096
#define BM 128
#define BN 128
#define BK 64

typedef __attribute__((ext_vector_type(8))) __bf16 bf16x8;
typedef __attribute__((ext_vector_type(4))) float f32x4;

__device__ __forceinline__ uint16_t f2bf_rn(float f) {
  uint32_t u = __builtin_bit_cast(uint32_t, f);
  u += 0x7FFFu + ((u >> 16) & 1u);
  return (uint16_t)(u >> 16);
}
__device__ __forceinline__ uint32_t pack2(uint16_t a, uint16_t b) {
  return (uint32_t)a | ((uint32_t)b << 16);
}
// x = hi + res, hi = RN_bf16(x); res = x - hi is EXACT in fp32 (Sterbenz);
// lo = RN_bf16(res). Total representation error <= 2^-16 relative.
__device__ __forceinline__ void hilo(float f, uint16_t& h, uint16_t& l) {
  h = f2bf_rn(f);
  float hf = __builtin_bit_cast(float, (uint32_t)h << 16);
  l = f2bf_rn(f - hf);
}
__device__ __forceinline__ void gload_lds16(const void* g, void* l) {
  __builtin_amdgcn_global_load_lds(
      (__attribute__((address_space(1))) void*)g,
      (__attribute__((address_space(3))) void*)l, 16, 0, 0);
}

// ---- prep: W int32 -> bf16 (exact; 0..126 fits bf16 mantissa) ----
__global__ __launch_bounds__(256) void prep_w_kernel(const int* __restrict__ wq,
                                                     uint16_t* __restrict__ wb) {
  const size_t total = (size_t)N_DIM * K_DIM;
  const size_t stride = (size_t)gridDim.x * 256 * 8;
  for (size_t idx = ((size_t)blockIdx.x * 256 + threadIdx.x) * 8; idx < total;
       idx += stride) {
    int4 a = *(const int4*)(wq + idx);
    int4 b = *(const int4*)(wq + idx + 4);
    uint4 o;
    o.x = pack2(f2bf_rn((float)a.x), f2bf_rn((float)a.y));
    o.y = pack2(f2bf_rn((float)a.z), f2bf_rn((float)a.w));
    o.z = pack2(f2bf_rn((float)b.x), f2bf_rn((float)b.y));
    o.w = pack2(f2bf_rn((float)b.z), f2bf_rn((float)b.w));
    *(uint4*)(wb + idx) = o;
  }
}

// ---- prep: X fp32 -> hi bf16 + lo bf16 ----
__global__ __launch_bounds__(256) void prep_x_kernel(const float* __restrict__ x,
                                                     uint16_t* __restrict__ hi,
                                                     uint16_t* __restrict__ lo) {
  const size_t total = (size_t)M_DIM * K_DIM;
  const size_t stride = (size_t)gridDim.x * 256 * 8;
  for (size_t idx = ((size_t)blockIdx.x * 256 + threadIdx.x) * 8; idx < total;
       idx += stride) {
    float4 v0 = *(const float4*)(x + idx);
    float4 v1 = *(const float4*)(x + idx + 4);
    uint16_t h[8], l[8];
    hilo(v0.x, h[0], l[0]); hilo(v0.y, h[1], l[1]);
    hilo(v0.z, h[2], l[2]); hilo(v0.w, h[3], l[3]);
    hilo(v1.x, h[4], l[4]); hilo(v1.y, h[5], l[5]);
    hilo(v1.z, h[6], l[6]); hilo(v1.w, h[7], l[7]);
    uint4 hv = {pack2(h[0],h[1]), pack2(h[2],h[3]), pack2(h[4],h[5]), pack2(h[6],h[7])};
    uint4 lv = {pack2(l[0],l[1]), pack2(l[2],l[3]), pack2(l[4],l[5]), pack2(l[6],l[7])};
    *(uint4*)(hi + idx) = hv;
    *(uint4*)(lo + idx) = lv;
  }
}

// ---- GEMM ----
// 256 threads = 4 waves (2x2), 64x64 out per wave, 4x4 16x16 fragments.
// BK=64 -> 2 mfma-K halves; hi and lo accumulate into the SAME fp32 acc.
// B fragment (bb) is loaded once per kk and reused by hi AND lo MFMAs.
template <bool PREP_A, bool PREP_W>
__global__ __launch_bounds__(256, 3) void qgemm(
    const float* __restrict__ X, const uint16_t* __restrict__ Ahi,
    const uint16_t* __restrict__ Alo, const int* __restrict__ Wq,
    const uint16_t* __restrict__ Wb, float* __restrict__ C) {
  __shared__ uint16_t sAhi[BM * BK];
  __shared__ uint16_t sAlo[BM * BK];
  __shared__ uint16_t sB[BN * BK];

  const int t = threadIdx.x;
  const int lane = t & 63;
  const int wid = t >> 6;
  const int wr = wid >> 1, wc = wid & 1;

  // T1: XCD-aware bijective swizzle (nwg = 2048 = 8 * 256).
  const int swz = (blockIdx.x & 7) * 256 + (blockIdx.x >> 3);
  const int bm = swz >> 5;  // 64 row-blocks
  const int bn = swz & 31;  // 32 col-blocks

  const int r = lane & 15;     // fragment row (A) / col (B)
  const int ksel = lane >> 4;  // k-quarter selector

  f32x4 acc[4][4];
#pragma unroll
  for (int m = 0; m < 4; ++m)
#pragma unroll
    for (int n = 0; n < 4; ++n) acc[m][n] = (f32x4){0.f, 0.f, 0.f, 0.f};

  const uint16_t* gAh = nullptr;
  const uint16_t* gAl = nullptr;
  const uint16_t* gB = nullptr;
  const float* gX = nullptr;
  const int* gW = nullptr;
  if constexpr (PREP_A) {
    size_t off = ((size_t)(bm * BM + (t >> 3))) * K_DIM + (t & 7) * 8;
    gAh = Ahi + off;
    gAl = Alo + off;
  } else {
    gX = X + ((size_t)(bm * BM + (t >> 1))) * K_DIM + (t & 1) * 32;
  }
  if constexpr (PREP_W) {
    gB = Wb + ((size_t)(bn * BN + (t >> 3))) * K_DIM + (t & 7) * 8;
  } else {
    gW = Wq + ((size_t)(bn * BN + (t >> 1))) * K_DIM + (t & 1) * 32;
  }

  const int arow = t >> 1;
  const int acol = (t & 1) * 32;

  for (int kt = 0; kt < K_DIM / BK; ++kt) {
    const int k0 = kt * BK;
    if constexpr (PREP_A) {
#pragma unroll
      for (int i = 0; i < 4; ++i) {
        gload_lds16(gAh + (size_t)i * 32 * K_DIM + k0,
                    (char*)sAhi + i * 4096 + wid * 1024);
        gload_lds16(gAl + (size_t)i * 32 * K_DIM + k0,
                    (char*)sAlo + i * 4096 + wid * 1024);
      }
    } else {
      const float* xp = gX + k0;
#pragma unroll
      for (int c = 0; c < 4; ++c) {
        float4 v0 = *(const float4*)(xp + c * 8);
        float4 v1 = *(const float4*)(xp + c * 8 + 4);
        uint16_t h[8], l[8];
        hilo(v0.x, h[0], l[0]); hilo(v0.y, h[1], l[1]);
        hilo(v0.z, h[2], l[2]); hilo(v0.w, h[3], l[3]);
        hilo(v1.x, h[4], l[4]); hilo(v1.y, h[5], l[5]);
        hilo(v1.z, h[6], l[6]); hilo(v1.w, h[7], l[7]);
        uint4 hv = {pack2(h[0], h[1]), pack2(h[2], h[3]), pack2(h[4], h[5]), pack2(h[6], h[7])};
        uint4 lv = {pack2(l[0], l[1]), pack2(l[2], l[3]), pack2(l[4], l[5]), pack2(l[6], l[7])};
        *(uint4*)&sAhi[arow * BK + acol + c * 8] = hv;
        *(uint4*)&sAlo[arow * BK + acol + c * 8] = lv;
      }
    }
    if constexpr (PREP_W) {
#pragma unroll
      for (int i = 0; i < 4; ++i)
        gload_lds16(gB + (size_t)i * 32 * K_DIM + k0,
                    (char*)sB + i * 4096 + wid * 1024);
    } else {
      const int* wp = gW + k0;
#pragma unroll
      for (int c = 0; c < 4; ++c) {
        int4 v0 = *(const int4*)(wp + c * 8);
        int4 v1 = *(const int4*)(wp + c * 8 + 4);
        uint4 bv = {pack2(f2bf_rn((float)v0.x), f2bf_rn((float)v0.y)),
                    pack2(f2bf_rn((float)v0.z), f2bf_rn((float)v0.w)),
                    pack2(f2bf_rn((float)v1.x), f2bf_rn((float)v1.y)),
                    pack2(f2bf_rn((float)v1.z), f2bf_rn((float)v1.w))};
        *(uint4*)&sB[arow * BK + acol + c * 8] = bv;
      }
    }
    __syncthreads();

#pragma unroll
    for (int kk = 0; kk < 2; ++kk) {
      bf16x8 ah[4], al[4], bb[4];
#pragma unroll
      for (int m = 0; m < 4; ++m)
        ah[m] = *(const bf16x8*)&sAhi[(wr * 64 + m * 16 + r) * BK + kk * 32 + ksel * 8];
#pragma unroll
      for (int n = 0; n < 4; ++n)
        bb[n] = *(const bf16x8*)&sB[(wc * 64 + n * 16 + r) * BK + kk * 32 + ksel * 8];
#pragma unroll
      for (int m = 0; m < 4; ++m)
        al[m] = *(const bf16x8*)&sAlo[(wr * 64 + m * 16 + r) * BK + kk * 32 + ksel * 8];
#pragma unroll
      for (int m = 0; m < 4; ++m)
#pragma unroll
        for (int n = 0; n < 4; ++n) {
          acc[m][n] = __builtin_amdgcn_mfma_f32_16x16x32_bf16(ah[m], bb[n], acc[m][n], 0, 0, 0);
          acc[m][n] = __builtin_amdgcn_mfma_f32_16x16x32_bf16(al[m], bb[n], acc[m][n], 0, 0, 0);
        }
    }
    __syncthreads();
  }

  // epilogue: C/D map col=lane&15, row=(lane>>4)*4+q (m89/m91 verified)
  const float sc = 1.0f / 127.0f;
  const size_t crow0 = (size_t)bm * BM + wr * 64 + ksel * 4;
  const int ccol0 = bn * BN + wc * 64 + r;
#pragma unroll
  for (int m = 0; m < 4; ++m)
#pragma unroll
    for (int n = 0; n < 4; ++n)
#pragma unroll
      for (int q = 0; q < 4; ++q)
        C[(crow0 + m * 16 + q) * (size_t)N_DIM + ccol0 + n * 16] = acc[m][n][q] * sc;
}

extern "C" void kernel_launch(void* const* d_in, const int* in_sizes, int n_in,
                              void* d_out, int out_size, void* d_ws, size_t ws_size,
                              hipStream_t stream) {
  const float* X = (const float*)d_in[0];
  const int* Wq = (const int*)d_in[1];
  float* C = (float*)d_out;

  const size_t wbytes = (size_t)N_DIM * K_DIM * 2;        // 32 MiB
  const size_t abytes = (size_t)M_DIM * K_DIM * 2;        // 64 MiB each
  const bool do_prep_w = ws_size >= wbytes;
  const bool do_prep_a = ws_size >= wbytes + 2 * abytes;  // 160 MiB

  uint16_t* Wb = (uint16_t*)d_ws;
  uint16_t* Ahi = (uint16_t*)((char*)d_ws + wbytes);
  uint16_t* Alo = Ahi + (size_t)M_DIM * K_DIM;

  if (do_prep_w)
    prep_w_kernel<<<2048, 256, 0, stream>>>(Wq, Wb);
  if (do_prep_a)
    prep_x_kernel<<<2048, 256, 0, stream>>>(X, Ahi, Alo);

  dim3 grid((M_DIM / BM) * (N_DIM / BN));  // 64*32 = 2048
  if (do_prep_a && do_prep_w)
    qgemm<true, true><<<grid, 256, 0, stream>>>(X, Ahi, Alo, Wq, Wb, C);
  else if (do_prep_w)
    qgemm<false, true><<<grid, 256, 0, stream>>>(X, Ahi, Alo, Wq, Wb, C);
  else
    qgemm<false, false><<<grid, 256, 0, stream>>>(X, Ahi, Alo, Wq, Wb, C);
}

// Round 8
// 707.229 us; speedup vs baseline: 1.0647x; 1.0647x over previous
//
#include <hip/hip_runtime.h>
#include <stdint.h>

// QuantizedLinear: C[8192,4096] = X[8192,4096] @ W[4096,4096]^T * (1/127)
// X split hi+lo bf16 (err <= 2^-16 rel), W exact bf16. m97-style 128x128xBK64
// MFMA GEMM, global_load_lds staging, T1 XCD swizzle.
// R7 (first green bench: qgemm 553us, MfmaUtil 45, VALU 16, BANK_CONFLICT
//     1.51e8): LDS pipe ~89% busy (590K issue + 590K conflict cyc/CU vs MFMA
//     636K) -> conflicts are the binding resource, NOT barrier drain.
//     Fix: rule-#21 XOR swizzle: linear LDS dest (gload_lds), global source
//     col pre-permuted by cb ^= ((row&7)<<4), same XOR on fragment reads.
//     Predict: conflicts <1e7, qgemm 380-430us, MfmaUtil ~60%.

#define M_DIM 8192
#define N_DIM 4096
#define K_DIM 4096
#define BM 128
#define BN 128
#define BK 64

typedef __attribute__((ext_vector_type(8))) __bf16 bf16x8;
typedef __attribute__((ext_vector_type(4))) float f32x4;

__device__ __forceinline__ uint16_t f2bf_rn(float f) {
  uint32_t u = __builtin_bit_cast(uint32_t, f);
  u += 0x7FFFu + ((u >> 16) & 1u);
  return (uint16_t)(u >> 16);
}
__device__ __forceinline__ uint32_t pack2(uint16_t a, uint16_t b) {
  return (uint32_t)a | ((uint32_t)b << 16);
}
// x = hi + res, hi = RN_bf16(x); res = x - hi EXACT in fp32; lo = RN_bf16(res).
__device__ __forceinline__ void hilo(float f, uint16_t& h, uint16_t& l) {
  h = f2bf_rn(f);
  float hf = __builtin_bit_cast(float, (uint32_t)h << 16);
  l = f2bf_rn(f - hf);
}
__device__ __forceinline__ void gload_lds16(const void* g, void* l) {
  __builtin_amdgcn_global_load_lds(
      (__attribute__((address_space(1))) void*)g,
      (__attribute__((address_space(3))) void*)l, 16, 0, 0);
}

// ---- prep: W int32 -> bf16 (exact; 0..126 fits bf16 mantissa) ----
__global__ __launch_bounds__(256) void prep_w_kernel(const int* __restrict__ wq,
                                                     uint16_t* __restrict__ wb) {
  const size_t total = (size_t)N_DIM * K_DIM;
  const size_t stride = (size_t)gridDim.x * 256 * 8;
  for (size_t idx = ((size_t)blockIdx.x * 256 + threadIdx.x) * 8; idx < total;
       idx += stride) {
    int4 a = *(const int4*)(wq + idx);
    int4 b = *(const int4*)(wq + idx + 4);
    uint4 o;
    o.x = pack2(f2bf_rn((float)a.x), f2bf_rn((float)a.y));
    o.y = pack2(f2bf_rn((float)a.z), f2bf_rn((float)a.w));
    o.z = pack2(f2bf_rn((float)b.x), f2bf_rn((float)b.y));
    o.w = pack2(f2bf_rn((float)b.z), f2bf_rn((float)b.w));
    *(uint4*)(wb + idx) = o;
  }
}

// ---- prep: X fp32 -> hi bf16 + lo bf16 ----
__global__ __launch_bounds__(256) void prep_x_kernel(const float* __restrict__ x,
                                                     uint16_t* __restrict__ hi,
                                                     uint16_t* __restrict__ lo) {
  const size_t total = (size_t)M_DIM * K_DIM;
  const size_t stride = (size_t)gridDim.x * 256 * 8;
  for (size_t idx = ((size_t)blockIdx.x * 256 + threadIdx.x) * 8; idx < total;
       idx += stride) {
    float4 v0 = *(const float4*)(x + idx);
    float4 v1 = *(const float4*)(x + idx + 4);
    uint16_t h[8], l[8];
    hilo(v0.x, h[0], l[0]); hilo(v0.y, h[1], l[1]);
    hilo(v0.z, h[2], l[2]); hilo(v0.w, h[3], l[3]);
    hilo(v1.x, h[4], l[4]); hilo(v1.y, h[5], l[5]);
    hilo(v1.z, h[6], l[6]); hilo(v1.w, h[7], l[7]);
    uint4 hv = {pack2(h[0],h[1]), pack2(h[2],h[3]), pack2(h[4],h[5]), pack2(h[6],h[7])};
    uint4 lv = {pack2(l[0],l[1]), pack2(l[2],l[3]), pack2(l[4],l[5]), pack2(l[6],l[7])};
    *(uint4*)(hi + idx) = hv;
    *(uint4*)(lo + idx) = lv;
  }
}

// ---- GEMM ----
// 256 threads = 4 waves (2x2), 64x64 out/wave, 4x4 16x16 fragments, BK=64.
// LDS layout swizzled: LDS[row][cb] = G[row][cb ^ ((row&7)<<4)] (bytes).
// Staging keeps LDS linear (gload_lds) and pre-permutes the GLOBAL col;
// fragment reads apply the same XOR -> 2-way-max bank access (free).
template <bool PREP_A, bool PREP_W>
__global__ __launch_bounds__(256, 3) void qgemm(
    const float* __restrict__ X, const uint16_t* __restrict__ Ahi,
    const uint16_t* __restrict__ Alo, const int* __restrict__ Wq,
    const uint16_t* __restrict__ Wb, float* __restrict__ C) {
  __shared__ uint16_t sAhi[BM * BK];
  __shared__ uint16_t sAlo[BM * BK];
  __shared__ uint16_t sB[BN * BK];

  const int t = threadIdx.x;
  const int lane = t & 63;
  const int wid = t >> 6;
  const int wr = wid >> 1, wc = wid & 1;

  // T1: XCD-aware bijective swizzle (nwg = 2048 = 8 * 256).
  const int swz = (blockIdx.x & 7) * 256 + (blockIdx.x >> 3);
  const int bm = swz >> 5;  // 64 row-blocks
  const int bn = swz & 31;  // 32 col-blocks

  const int r = lane & 15;     // fragment row (A) / col (B)
  const int ksel = lane >> 4;  // k-quarter selector
  const int rx = (r & 7) * 8;  // read-side XOR mask (elements)

  f32x4 acc[4][4];
#pragma unroll
  for (int m = 0; m < 4; ++m)
#pragma unroll
    for (int n = 0; n < 4; ++n) acc[m][n] = (f32x4){0.f, 0.f, 0.f, 0.f};

  // staging: thread t fills LDS (row = t>>3, colbyte = (t&7)*16) per subtile;
  // source col element = ((t&7) ^ ((t>>3)&7)) * 8  (inverse == same XOR).
  const int csel = (((t & 7) ^ ((t >> 3) & 7)) * 8);

  const uint16_t* gAh = nullptr;
  const uint16_t* gAl = nullptr;
  const uint16_t* gB = nullptr;
  const float* gX = nullptr;
  const int* gW = nullptr;
  if constexpr (PREP_A) {
    size_t off = ((size_t)(bm * BM + (t >> 3))) * K_DIM + csel;
    gAh = Ahi + off;
    gAl = Alo + off;
  } else {
    gX = X + ((size_t)(bm * BM + (t >> 1))) * K_DIM + (t & 1) * 32;
  }
  if constexpr (PREP_W) {
    gB = Wb + ((size_t)(bn * BN + (t >> 3))) * K_DIM + csel;
  } else {
    gW = Wq + ((size_t)(bn * BN + (t >> 1))) * K_DIM + (t & 1) * 32;
  }

  const int arow = t >> 1;          // fallback-path row (0..127)
  const int acol = (t & 1) * 32;    // fallback-path col base
  const int awx = (arow & 7) * 8;   // fallback-path write XOR mask

  for (int kt = 0; kt < K_DIM / BK; ++kt) {
    const int k0 = kt * BK;
    if constexpr (PREP_A) {
#pragma unroll
      for (int i = 0; i < 4; ++i) {
        gload_lds16(gAh + (size_t)i * 32 * K_DIM + k0,
                    (char*)sAhi + i * 4096 + wid * 1024);
        gload_lds16(gAl + (size_t)i * 32 * K_DIM + k0,
                    (char*)sAlo + i * 4096 + wid * 1024);
      }
    } else {
      const float* xp = gX + k0;
#pragma unroll
      for (int c = 0; c < 4; ++c) {
        float4 v0 = *(const float4*)(xp + c * 8);
        float4 v1 = *(const float4*)(xp + c * 8 + 4);
        uint16_t h[8], l[8];
        hilo(v0.x, h[0], l[0]); hilo(v0.y, h[1], l[1]);
        hilo(v0.z, h[2], l[2]); hilo(v0.w, h[3], l[3]);
        hilo(v1.x, h[4], l[4]); hilo(v1.y, h[5], l[5]);
        hilo(v1.z, h[6], l[6]); hilo(v1.w, h[7], l[7]);
        uint4 hv = {pack2(h[0], h[1]), pack2(h[2], h[3]), pack2(h[4], h[5]), pack2(h[6], h[7])};
        uint4 lv = {pack2(l[0], l[1]), pack2(l[2], l[3]), pack2(l[4], l[5]), pack2(l[6], l[7])};
        const int wcol = (acol + c * 8) ^ awx;
        *(uint4*)&sAhi[arow * BK + wcol] = hv;
        *(uint4*)&sAlo[arow * BK + wcol] = lv;
      }
    }
    if constexpr (PREP_W) {
#pragma unroll
      for (int i = 0; i < 4; ++i)
        gload_lds16(gB + (size_t)i * 32 * K_DIM + k0,
                    (char*)sB + i * 4096 + wid * 1024);
    } else {
      const int* wp = gW + k0;
#pragma unroll
      for (int c = 0; c < 4; ++c) {
        int4 v0 = *(const int4*)(wp + c * 8);
        int4 v1 = *(const int4*)(wp + c * 8 + 4);
        uint4 bv = {pack2(f2bf_rn((float)v0.x), f2bf_rn((float)v0.y)),
                    pack2(f2bf_rn((float)v0.z), f2bf_rn((float)v0.w)),
                    pack2(f2bf_rn((float)v1.x), f2bf_rn((float)v1.y)),
                    pack2(f2bf_rn((float)v1.z), f2bf_rn((float)v1.w))};
        *(uint4*)&sB[arow * BK + ((acol + c * 8) ^ awx)] = bv;
      }
    }
    __syncthreads();

#pragma unroll
    for (int kk = 0; kk < 2; ++kk) {
      const int kcol = (kk * 32 + ksel * 8) ^ rx;  // swizzled fragment col
      bf16x8 ah[4], al[4], bb[4];
#pragma unroll
      for (int m = 0; m < 4; ++m)
        ah[m] = *(const bf16x8*)&sAhi[(wr * 64 + m * 16 + r) * BK + kcol];
#pragma unroll
      for (int n = 0; n < 4; ++n)
        bb[n] = *(const bf16x8*)&sB[(wc * 64 + n * 16 + r) * BK + kcol];
#pragma unroll
      for (int m = 0; m < 4; ++m)
        al[m] = *(const bf16x8*)&sAlo[(wr * 64 + m * 16 + r) * BK + kcol];
#pragma unroll
      for (int m = 0; m < 4; ++m)
#pragma unroll
        for (int n = 0; n < 4; ++n) {
          acc[m][n] = __builtin_amdgcn_mfma_f32_16x16x32_bf16(ah[m], bb[n], acc[m][n], 0, 0, 0);
          acc[m][n] = __builtin_amdgcn_mfma_f32_16x16x32_bf16(al[m], bb[n], acc[m][n], 0, 0, 0);
        }
    }
    __syncthreads();
  }

  // epilogue: C/D map col=lane&15, row=(lane>>4)*4+q (m89/m91 verified)
  const float sc = 1.0f / 127.0f;
  const size_t crow0 = (size_t)bm * BM + wr * 64 + ksel * 4;
  const int ccol0 = bn * BN + wc * 64 + r;
#pragma unroll
  for (int m = 0; m < 4; ++m)
#pragma unroll
    for (int n = 0; n < 4; ++n)
#pragma unroll
      for (int q = 0; q < 4; ++q)
        C[(crow0 + m * 16 + q) * (size_t)N_DIM + ccol0 + n * 16] = acc[m][n][q] * sc;
}

extern "C" void kernel_launch(void* const* d_in, const int* in_sizes, int n_in,
                              void* d_out, int out_size, void* d_ws, size_t ws_size,
                              hipStream_t stream) {
  const float* X = (const float*)d_in[0];
  const int* Wq = (const int*)d_in[1];
  float* C = (float*)d_out;

  const size_t wbytes = (size_t)N_DIM * K_DIM * 2;        // 32 MiB
  const size_t abytes = (size_t)M_DIM * K_DIM * 2;        // 64 MiB each
  const bool do_prep_w = ws_size >= wbytes;
  const bool do_prep_a = ws_size >= wbytes + 2 * abytes;  // 160 MiB

  uint16_t* Wb = (uint16_t*)d_ws;
  uint16_t* Ahi = (uint16_t*)((char*)d_ws + wbytes);
  uint16_t* Alo = Ahi + (size_t)M_DIM * K_DIM;

  if (do_prep_w)
    prep_w_kernel<<<2048, 256, 0, stream>>>(Wq, Wb);
  if (do_prep_a)
    prep_x_kernel<<<2048, 256, 0, stream>>>(X, Ahi, Alo);

  dim3 grid((M_DIM / BM) * (N_DIM / BN));  // 64*32 = 2048
  if (do_prep_a && do_prep_w)
    qgemm<true, true><<<grid, 256, 0, stream>>>(X, Ahi, Alo, Wq, Wb, C);
  else if (do_prep_w)
    qgemm<false, true><<<grid, 256, 0, stream>>>(X, Ahi, Alo, Wq, Wb, C);
  else
    qgemm<false, false><<<grid, 256, 0, stream>>>(X, Ahi, Alo, Wq, Wb, C);
}